// Round 4
// baseline (429.153 us; speedup 1.0000x reference)
//
#include <hip/hip_runtime.h>

#define NT 256            // 1 output column per thread
#define RROWS 45          // output rows per block (multiple of 9!)
#define STRIP 256         // output cols per block
#define PW 264            // staged (x,y) pairs per row: STRIP + 8 halo
#define NLD 132           // loader threads: PW/2 float4 chunks
#define WID 1024
#define HEI 1024
#define OWD 1016          // valid conv output dim (1024 - 8)

typedef float v2f __attribute__((ext_vector_type(2)));

// compile-time for: indices are literal constants in the AST -> SROA-proof
template<int I> struct IC { static constexpr int v = I; };
template<int N, int I = 0, typename F>
__device__ __forceinline__ void sfor(F&& f) {
    if constexpr (I < N) { f(IC<I>{}); sfor<N, I + 1>(f); }
}

static __device__ __forceinline__ v2f pkfma(v2f a, v2f b, v2f c) {
#if __has_builtin(__builtin_elementwise_fma)
    return __builtin_elementwise_fma(a, b, c);   // -> v_pk_fma_f32
#else
    v2f r; r.x = fmaf(a.x, b.x, c.x); r.y = fmaf(a.y, b.y, c.y); return r;
#endif
}

__global__ __launch_bounds__(NT, 2)   // budget 256 VGPR: ~88 used, zero spill
void ssim_main(const float* __restrict__ X, const float* __restrict__ Y,
               const float* __restrict__ Wg, double* __restrict__ acc)
{
    // 9-row LDS ring: Prow[row%9][col] = (x_col, y_col). Phase p writes rows
    // 3p+9..3p+11 (slots {3q,3q+1,3q+2} mod 9), phase p reads rows 3p+8..3p+10
    // -> phase p+1 writes never touch phase p reads: ONE barrier per phase.
    // NEW vs R0: 6-row pending pipeline (banks A=slots0..2, B=slots3..5).
    // Phase p stores rows issued at phase p-2 -> prefetch distance ~2 phases
    // (~1400 cyc) > HBM miss latency (~900 cyc): no vmcnt drain at the store.
    __shared__ float2 Prow[9][PW];
    __shared__ float  wsum[4][2];

    const int t  = threadIdx.x;
    const int r0 = blockIdx.x * RROWS;          // multiple of 9
    const int c0 = blockIdx.y * STRIP;
    const size_t ibase = (size_t)blockIdx.z * (size_t)(WID * HEI);

    const int lc   = t;                                   // loader chunk (0 conflicts)
    const bool ldv  = (lc < NLD) && (c0 + 2 * lc < WID);  // loader role
    const bool ownc = (lc < STRIP / 2);                   // halo chunks not owned

    // 1D gaussian from row 4 of w2d: w2d[4][k] = g4*g[k], row sum = g4
    float g[9];
    {
        float s = 0.f;
        sfor<9>([&](auto K) { constexpr int k = decltype(K)::v;
            g[k] = Wg[36 + k]; s += g[k]; });
        float rs = __builtin_amdgcn_rcpf(s);
        sfor<9>([&](auto K) { constexpr int k = decltype(K)::v; g[k] *= rs; });
    }

    const float C1 = 0.0004f, C2 = 0.0036f;
    float ssim_acc = 0.f, l1_acc = 0.f;

    // register ring of horizontal-conv rows (45 VGPRs) + 6-row pending pipeline
    v2f  r01[9], r23[9];
    float r4[9];
    float2 pbx[6], pby[6];

    const float2* __restrict__ Xp = (const float2*)(X + ibase + c0);
    const float2* __restrict__ Yp = (const float2*)(Y + ibase + c0);

    auto issue = [&](int ro, auto S) {        // load row r0+ro -> pending slot s
        constexpr int s = decltype(S)::v;
        const int row = r0 + ro;
        if (ldv && row < HEI) {
            pbx[s] = Xp[(size_t)row * (WID / 2) + lc];
            pby[s] = Yp[(size_t)row * (WID / 2) + lc];
        }
    };
    auto store = [&](int ro, auto S, auto LS) {  // pending slot s -> LDS slot ls
        constexpr int s  = decltype(S)::v;
        constexpr int ls = decltype(LS)::v;
        const int row = r0 + ro;
        if (ldv && row < HEI) {
            float4* dst = (float4*)&Prow[ls][2 * lc];
            *dst = make_float4(pbx[s].x, pby[s].x, pbx[s].y, pby[s].y);
            if (ownc && ro < RROWS)   // L1 over exclusively-owned rows/cols
                l1_acc += fabsf(pbx[s].x - pby[s].x) + fabsf(pbx[s].y - pby[s].y);
        }
    };
    auto hcomp = [&](auto LS, auto RS) {      // horizontal 9-tap, LDS -> ring
        constexpr int ls = decltype(LS)::v;
        constexpr int rs = decltype(RS)::v;
        v2f s01 = (v2f)0.f, s23 = (v2f)0.f; float s4 = 0.f;
        sfor<9>([&](auto K) { constexpr int k = decltype(K)::v;
            float2 p = Prow[ls][t + k];
            v2f a = { p.x, p.y };
            v2f gk2 = { g[k], g[k] };
            s01 = pkfma(gk2, a, s01);
            s23 = pkfma(gk2, a * a, s23);
            s4  = fmaf(g[k], p.x * p.y, s4);
        });
        r01[rs] = s01; r23[rs] = s23; r4[rs] = s4;
    };

    const bool vA = (c0 + t < OWD);

    auto outrow = [&](int j, auto JM) {       // vertical 9-tap + SSIM for row j
        constexpr int jm = decltype(JM)::v;
        if (r0 + j < OWD) {                   // block-uniform guard
            v2f u01 = (v2f)0.f, u23 = (v2f)0.f; float u4 = 0.f;
            sfor<9>([&](auto K) { constexpr int k = decltype(K)::v;
                constexpr int s = (jm + k) % 9;
                v2f gk2 = { g[k], g[k] };
                u01 = pkfma(gk2, r01[s], u01);
                u23 = pkfma(gk2, r23[s], u23);
                u4  = fmaf(g[k], r4[s], u4);
            });
            float ux = u01.x, uy = u01.y, uxx = u23.x, uyy = u23.y, uxy = u4;
            float uxux = ux * ux, uyuy = uy * uy, uxuy = ux * uy;
            float A1 = 2.f * uxuy + C1;
            float A2 = 2.f * (uxy - uxuy) + C2;
            float B1 = uxux + uyuy + C1;
            float B2 = (uxx - uxux) + (uyy - uyuy) + C2;
            float S  = (A1 * A2) * __builtin_amdgcn_rcpf(B1 * B2);
            ssim_acc += vA ? S : 0.f;
        }
    };

    // ---- prologue: rows 0..8 staged+hcomp'd (row 8's hcomp deferred),
    //      rows 9..14 in flight (banks B then A) before steady state
    issue(0, IC<0>{}); issue(1, IC<1>{}); issue(2, IC<2>{});
    issue(3, IC<3>{}); issue(4, IC<4>{}); issue(5, IC<5>{});
    store(0, IC<0>{}, IC<0>{}); store(1, IC<1>{}, IC<1>{}); store(2, IC<2>{}, IC<2>{});
    __syncthreads();
    issue(6, IC<0>{}); issue(7, IC<1>{}); issue(8, IC<2>{});
    hcomp(IC<0>{}, IC<0>{}); hcomp(IC<1>{}, IC<1>{}); hcomp(IC<2>{}, IC<2>{});
    store(3, IC<3>{}, IC<3>{}); store(4, IC<4>{}, IC<4>{}); store(5, IC<5>{}, IC<5>{});
    __syncthreads();
    issue(9, IC<3>{}); issue(10, IC<4>{}); issue(11, IC<5>{});
    hcomp(IC<3>{}, IC<3>{}); hcomp(IC<4>{}, IC<4>{}); hcomp(IC<5>{}, IC<5>{});
    store(6, IC<0>{}, IC<6>{}); store(7, IC<1>{}, IC<7>{}); store(8, IC<2>{}, IC<8>{});
    __syncthreads();
    issue(12, IC<0>{}); issue(13, IC<1>{}); issue(14, IC<2>{});
    hcomp(IC<6>{}, IC<6>{}); hcomp(IC<7>{}, IC<7>{});

    // ---- steady: 15 phases of 3 output rows; one barrier per phase.
    // Q3 = p%3 (LDS ring slots), Q2 = p%2 (pending bank: even p -> B=3..5).
    auto phase = [&](int p, auto Q3c, auto Q2c) {
        constexpr int Q3 = decltype(Q3c)::v;
        constexpr int Q2 = decltype(Q2c)::v;
        constexpr int PB = Q2 ? 0 : 3;
        const int j0 = 3 * p;
        // stage rows 3p+9..3p+11 (issued two phases ago)
        store(j0 + 9,  IC<PB + 0>{}, IC<(3 * Q3) % 9>{});
        store(j0 + 10, IC<PB + 1>{}, IC<(3 * Q3 + 1) % 9>{});
        store(j0 + 11, IC<PB + 2>{}, IC<(3 * Q3 + 2) % 9>{});
        __syncthreads();
        if (p < 13) {   // prefetch rows 3p+15..3p+17 (consumed at phase p+2)
            issue(j0 + 15, IC<PB + 0>{});
            issue(j0 + 16, IC<PB + 1>{});
            issue(j0 + 17, IC<PB + 2>{});
        }
        hcomp(IC<(3 * Q3 + 8) % 9>{}, IC<(3 * Q3 + 8) % 9>{});
        outrow(j0,     IC<(3 * Q3) % 9>{});
        hcomp(IC<(3 * Q3 + 9) % 9>{}, IC<(3 * Q3 + 9) % 9>{});
        outrow(j0 + 1, IC<(3 * Q3 + 1) % 9>{});
        hcomp(IC<(3 * Q3 + 10) % 9>{}, IC<(3 * Q3 + 10) % 9>{});
        outrow(j0 + 2, IC<(3 * Q3 + 2) % 9>{});
    };

#pragma unroll 1
    for (int P6 = 0; P6 < 2; ++P6) {
        const int pb = 6 * P6;
        phase(pb + 0, IC<0>{}, IC<0>{});
        phase(pb + 1, IC<1>{}, IC<1>{});
        phase(pb + 2, IC<2>{}, IC<0>{});
        phase(pb + 3, IC<0>{}, IC<1>{});
        phase(pb + 4, IC<1>{}, IC<0>{});
        phase(pb + 5, IC<2>{}, IC<1>{});
    }
    phase(12, IC<0>{}, IC<0>{});
    phase(13, IC<1>{}, IC<1>{});
    phase(14, IC<2>{}, IC<0>{});

    // ---- reduction: wave shfl -> LDS -> one double atomic pair per block
#pragma unroll
    for (int off = 32; off > 0; off >>= 1) {
        ssim_acc += __shfl_down(ssim_acc, off);
        l1_acc   += __shfl_down(l1_acc, off);
    }
    const int wid = t >> 6;
    if ((t & 63) == 0) { wsum[wid][0] = ssim_acc; wsum[wid][1] = l1_acc; }
    __syncthreads();
    if (t == 0) {
        double s = 0.0, l = 0.0;
#pragma unroll
        for (int w = 0; w < 4; ++w) { s += (double)wsum[w][0]; l += (double)wsum[w][1]; }
        atomicAdd(acc + 0, s);
        atomicAdd(acc + 1, l);
    }
}

__global__ void ssim_final(const double* __restrict__ acc, float* __restrict__ out)
{
    const double n_ssim = 33032192.0;   // 32*1016*1016
    const double n_l1   = 33554432.0;   // 32*1024*1024
    double ssim_loss = 1.0 - acc[0] / n_ssim;
    double l1        = acc[1] / n_l1;
    out[0] = (float)(0.5 * ssim_loss + 1.0 * l1);
}

extern "C" void kernel_launch(void* const* d_in, const int* in_sizes, int n_in,
                              void* d_out, int out_size, void* d_ws, size_t ws_size,
                              hipStream_t stream)
{
    const float* X  = (const float*)d_in[0];
    const float* Y  = (const float*)d_in[1];
    const float* Wg = (const float*)d_in[2];
    float*  out = (float*)d_out;
    double* acc = (double*)d_ws;

    hipMemsetAsync(acc, 0, 2 * sizeof(double), stream);
    dim3 grid(23, 4, 32);   // rowblocks(ceil(1016/45)) x col-strips x images
    ssim_main<<<grid, NT, 0, stream>>>(X, Y, Wg, acc);
    ssim_final<<<1, 1, 0, stream>>>(acc, out);
}

// Round 5
// 342.620 us; speedup vs baseline: 1.2526x; 1.2526x over previous
//
#include <hip/hip_runtime.h>

#define NT 256            // 1 output column per thread, 4 waves
#define RROWS 45          // output rows per block (multiple of 9!)
#define STRIP 256         // output cols per block
#define PWL 264           // staged floats per row: STRIP + 8 halo (1056 B, 16B-mult)
#define NRING 12          // LDS row ring (9 live + 2-phase DMA in flight)
#define WID 1024
#define HEI 1024
#define OWD 1016          // valid conv output dim (1024 - 8)

typedef float v2f __attribute__((ext_vector_type(2)));

// compile-time for: indices are literal constants in the AST -> SROA-proof
template<int I> struct IC { static constexpr int v = I; };
template<int N, int I = 0, typename F>
__device__ __forceinline__ void sfor(F&& f) {
    if constexpr (I < N) { f(IC<I>{}); sfor<N, I + 1>(f); }
}

static __device__ __forceinline__ v2f pkfma(v2f a, v2f b, v2f c) {
#if __has_builtin(__builtin_elementwise_fma)
    return __builtin_elementwise_fma(a, b, c);   // -> v_pk_fma_f32
#else
    v2f r; r.x = fmaf(a.x, b.x, c.x); r.y = fmaf(a.y, b.y, c.y); return r;
#endif
}

typedef __attribute__((address_space(1))) const void gvoid_t;
typedef __attribute__((address_space(3))) void svoid_t;

// direct global->LDS DMA, 16 B/lane (64 lanes = 1024 B). LDS dest is
// wave-uniform base + lane*16 (m104); no VGPR round-trip -> the compiler
// cannot sink the prefetch toward its use (R4's failure mode).
static __device__ __forceinline__ void gld16(const float* gp, float* lp) {
    __builtin_amdgcn_global_load_lds((gvoid_t*)gp, (svoid_t*)lp, 16, 0, 0);
}

__global__ __launch_bounds__(NT, 2)   // honest allocation (R0-proven); ~70 VGPR
void ssim_main(const float* __restrict__ X, const float* __restrict__ Y,
               const float* __restrict__ Wg, double* __restrict__ acc)
{
    // SoA rings (DMA copies contiguous bytes, so X/Y can't interleave).
    // Slot = input_row % 12. Phase p computes output rows 3p..3p+2, hcomps
    // input rows 3p+8..10, DMAs rows 3p+15..17 (consumed at phase p+2 ->
    // ~1200 cyc in flight > 900 cyc HBM latency). Slots written at phase p
    // were last read at phase p-2 -> race-free with one barrier per phase.
    __shared__ __align__(16) float Xr[NRING][PWL];
    __shared__ __align__(16) float Yr[NRING][PWL];
    __shared__ float wsum[4][2];

    const int t    = threadIdx.x;
    const int wv   = t >> 6, lane = t & 63;
    const int r0   = blockIdx.x * RROWS;        // multiple of 9
    const int c0   = blockIdx.y * STRIP;
    const size_t ibase = (size_t)blockIdx.z * (size_t)(WID * HEI);

    const float* __restrict__ Xg = X + ibase + c0;
    const float* __restrict__ Yg = Y + ibase + c0;
    // halo source: cols c0+256..263 when in-bounds; else safe dummy (feeds
    // only vA-guarded invalid outputs)
    const int remoff = (c0 + PWL <= WID) ? STRIP : 0;

    // wave roles: wv0 = X main (64x16B), wv1 = X halo (2x16B), wv2/3 = Y same.
    // EVERY wave issues exactly 1 DMA per staged row -> uniform per-wave vmcnt.
    auto dma = [&](int ro) {
        const int row = r0 + ro;
        if (row >= HEI) return;                 // block-uniform
        const int sl = (unsigned)ro % NRING;
        if (wv == 0)      gld16(Xg + (size_t)row * WID + lane * 4, &Xr[sl][0]);
        else if (wv == 1) { if (lane < 2) gld16(Xg + (size_t)row * WID + remoff + lane * 4, &Xr[sl][STRIP]); }
        else if (wv == 2) gld16(Yg + (size_t)row * WID + lane * 4, &Yr[sl][0]);
        else              { if (lane < 2) gld16(Yg + (size_t)row * WID + remoff + lane * 4, &Yr[sl][STRIP]); }
    };

    // counted-vmcnt sync (T4): never drain to 0 in the main loop.
    auto wait_barrier = [&](bool drain0, bool w6) {
        if (drain0)  asm volatile("s_waitcnt vmcnt(0)" ::: "memory");
        else if (w6) asm volatile("s_waitcnt vmcnt(6)" ::: "memory");
        else         asm volatile("s_waitcnt vmcnt(3)" ::: "memory");
        __builtin_amdgcn_s_barrier();
        asm volatile("" ::: "memory");          // no LDS reads hoist above barrier
    };

    // 1D gaussian from row 4 of w2d: w2d[4][k] = g4*g[k], row sum = g4
    float g[9];
    {
        float s = 0.f;
        sfor<9>([&](auto K) { constexpr int k = decltype(K)::v;
            g[k] = Wg[36 + k]; s += g[k]; });
        float rs = __builtin_amdgcn_rcpf(s);
        sfor<9>([&](auto K) { constexpr int k = decltype(K)::v; g[k] *= rs; });
    }

    const float C1 = 0.0004f, C2 = 0.0036f;
    float ssim_acc = 0.f, l1_acc = 0.f;

    // register ring of horizontal-conv rows (45 VGPRs); no pending regs anymore
    v2f  r01[9], r23[9];
    float r4[9];

    // L1 over newly-landed rows; thread t owns col c0+t exclusively
    auto l1row = [&](int ro) {
        const int row = r0 + ro;
        if (ro < RROWS && row < HEI) {
            const int sl = (unsigned)ro % NRING;
            l1_acc += fabsf(Xr[sl][t] - Yr[sl][t]);
        }
    };

    auto hcomp = [&](int sl, auto RS) {       // horizontal 9-tap, SoA LDS -> ring
        constexpr int rs = decltype(RS)::v;
        const float* xb = &Xr[sl][t];
        const float* yb = &Yr[sl][t];
        v2f s01 = (v2f)0.f, s23 = (v2f)0.f; float s4 = 0.f;
        sfor<9>([&](auto K) { constexpr int k = decltype(K)::v;
            float x = xb[k], y = yb[k];
            v2f a = { x, y };
            v2f gk2 = { g[k], g[k] };
            s01 = pkfma(gk2, a, s01);
            s23 = pkfma(gk2, a * a, s23);
            s4  = fmaf(g[k], x * y, s4);
        });
        r01[rs] = s01; r23[rs] = s23; r4[rs] = s4;
    };

    const bool vA = (c0 + t < OWD);

    auto outrow = [&](int j, auto JM) {       // vertical 9-tap + SSIM for row j
        constexpr int jm = decltype(JM)::v;
        if (r0 + j < OWD) {                   // block-uniform guard
            v2f u01 = (v2f)0.f, u23 = (v2f)0.f; float u4 = 0.f;
            sfor<9>([&](auto K) { constexpr int k = decltype(K)::v;
                constexpr int s = (jm + k) % 9;
                v2f gk2 = { g[k], g[k] };
                u01 = pkfma(gk2, r01[s], u01);
                u23 = pkfma(gk2, r23[s], u23);
                u4  = fmaf(g[k], r4[s], u4);
            });
            float ux = u01.x, uy = u01.y, uxx = u23.x, uyy = u23.y, uxy = u4;
            float uxux = ux * ux, uyuy = uy * uy, uxuy = ux * uy;
            float A1 = 2.f * uxuy + C1;
            float A2 = 2.f * (uxy - uxuy) + C2;
            float B1 = uxux + uyuy + C1;
            float B2 = (uxx - uxux) + (uyy - uyuy) + C2;
            float S  = (A1 * A2) * __builtin_amdgcn_rcpf(B1 * B2);
            ssim_acc += vA ? S : 0.f;
        }
    };

    // ---- prologue: batches b0..b4 (rows 0..14) in flight; hcomp rows 0..7
    dma(0); dma(1); dma(2);                   // b0
    dma(3); dma(4); dma(5);                   // b1
    dma(6); dma(7); dma(8);                   // b2
    wait_barrier(false, true);                // vmcnt(6): b0 landed
    dma(9); dma(10); dma(11);                 // b3
    l1row(0); l1row(1); l1row(2);
    hcomp(0, IC<0>{}); hcomp(1, IC<1>{}); hcomp(2, IC<2>{});
    wait_barrier(false, true);                // vmcnt(6): b1 landed
    dma(12); dma(13); dma(14);                // b4
    l1row(3); l1row(4); l1row(5);
    hcomp(3, IC<3>{}); hcomp(4, IC<4>{}); hcomp(5, IC<5>{});
    wait_barrier(false, true);                // vmcnt(6): b2 landed (b3,b4 fly)
    l1row(6); l1row(7); l1row(8);
    hcomp(6, IC<6>{}); hcomp(7, IC<7>{});     // row 8's hcomp deferred to steady

    // last row-block may skip edge DMAs -> per-wave counts shift; drain there
    const bool vtail = (r0 + 59 >= HEI);

    // ---- steady: 15 phases of 3 output rows; one raw barrier per phase
#pragma unroll 1
    for (int P = 0; P < 5; ++P) {
        sfor<3>([&](auto Q) {
            constexpr int q = decltype(Q)::v;
            const int p   = 3 * P + q;
            const int j0  = 3 * p;
            const int ro8 = j0 + 8;
            // vmcnt(3): batch p+3 (rows 3p+9..11) landed; batch p+4 stays in flight
            wait_barrier(vtail || p == 14, false);
            if (p <= 12) { dma(j0 + 15); dma(j0 + 16); dma(j0 + 17); }  // batch p+5
            l1row(j0 + 9); l1row(j0 + 10); l1row(j0 + 11);
            hcomp((unsigned)(ro8)     % NRING, IC<(3 * q + 8) % 9>{});
            outrow(j0,     IC<(3 * q) % 9>{});
            hcomp((unsigned)(ro8 + 1) % NRING, IC<(3 * q + 9) % 9>{});
            outrow(j0 + 1, IC<(3 * q + 1) % 9>{});
            hcomp((unsigned)(ro8 + 2) % NRING, IC<(3 * q + 10) % 9>{});
            outrow(j0 + 2, IC<(3 * q + 2) % 9>{});
        });
    }

    // ---- reduction: wave shfl -> LDS -> one double atomic pair per block
    // (phase 14 drained vmcnt(0); __syncthreads here is safe and simple)
#pragma unroll
    for (int off = 32; off > 0; off >>= 1) {
        ssim_acc += __shfl_down(ssim_acc, off);
        l1_acc   += __shfl_down(l1_acc, off);
    }
    const int wid = t >> 6;
    if ((t & 63) == 0) { wsum[wid][0] = ssim_acc; wsum[wid][1] = l1_acc; }
    __syncthreads();
    if (t == 0) {
        double s = 0.0, l = 0.0;
#pragma unroll
        for (int w = 0; w < 4; ++w) { s += (double)wsum[w][0]; l += (double)wsum[w][1]; }
        atomicAdd(acc + 0, s);
        atomicAdd(acc + 1, l);
    }
}

__global__ void ssim_final(const double* __restrict__ acc, float* __restrict__ out)
{
    const double n_ssim = 33032192.0;   // 32*1016*1016
    const double n_l1   = 33554432.0;   // 32*1024*1024
    double ssim_loss = 1.0 - acc[0] / n_ssim;
    double l1        = acc[1] / n_l1;
    out[0] = (float)(0.5 * ssim_loss + 1.0 * l1);
}

extern "C" void kernel_launch(void* const* d_in, const int* in_sizes, int n_in,
                              void* d_out, int out_size, void* d_ws, size_t ws_size,
                              hipStream_t stream)
{
    const float* X  = (const float*)d_in[0];
    const float* Y  = (const float*)d_in[1];
    const float* Wg = (const float*)d_in[2];
    float*  out = (float*)d_out;
    double* acc = (double*)d_ws;

    hipMemsetAsync(acc, 0, 2 * sizeof(double), stream);
    dim3 grid(23, 4, 32);   // rowblocks(ceil(1016/45)) x col-strips x images
    ssim_main<<<grid, NT, 0, stream>>>(X, Y, Wg, acc);
    ssim_final<<<1, 1, 0, stream>>>(acc, out);
}